// Round 3
// baseline (328.131 us; speedup 1.0000x reference)
//
#include <hip/hip_runtime.h>
#include <hip/hip_bf16.h>

// Problem constants
#define BB_   8
#define DIM_  512
#define LIN_  4096
#define LOUT_ 8192

typedef __attribute__((ext_vector_type(8))) __bf16 bf16x8;
typedef __attribute__((ext_vector_type(4))) float  f32x4;
typedef __attribute__((ext_vector_type(8))) unsigned short u16x8;

__device__ __forceinline__ float bf2f(unsigned short u) {
  union { unsigned int i; float f; } x;
  x.i = ((unsigned int)u) << 16;
  return x.f;
}

// RNE float->bf16
__device__ __forceinline__ unsigned short f2bf(float f) {
  unsigned int u = __float_as_uint(f);
  return (unsigned short)((u + 0x7fffu + ((u >> 16) & 1u)) >> 16);
}

// async global->LDS, 16B per lane; LDS dest = wave-uniform base + lane*16
__device__ __forceinline__ void gload16(const void* g, void* l) {
  __builtin_amdgcn_global_load_lds(
      (__attribute__((address_space(1))) void*)(g),
      (__attribute__((address_space(3))) void*)(l), 16, 0, 0);
}

// ---------------------------------------------------------------------------
// 1) k_prep — heterogeneous grid, 4416 blocks (unchanged):
//    [0,192):    Mst[kk*512+e][i] = sum_d proj_w[e,d]*conv_w[d,i,kk]  (bf16)
//    [192,320):  Pcb[e] = sum_d proj_w[e,d]*conv_b[d]
//    [320,4416): Xbt[b][l][d] = bf16(x[b][d][l])
__global__ __launch_bounds__(256) void k_prep(const float* __restrict__ proj_w,
                                              const float* __restrict__ conv_w,
                                              const float* __restrict__ conv_b,
                                              const float* __restrict__ x,
                                              unsigned short* __restrict__ Mst,
                                              float* __restrict__ Pcb,
                                              unsigned short* __restrict__ Xbt) {
  __shared__ __align__(16) float sm[4160];
  const int bx  = blockIdx.x;
  const int tid = threadIdx.x;

  if (bx < 192) {
    float* Pt = sm;           // [16][68]
    float* Wt = sm + 1088;    // [16][68]
    const int kk = bx >> 6;
    const int t6 = bx & 63;
    const int et = (t6 >> 3) << 6;
    const int it = (t6 & 7) << 6;
    const int tx = tid & 15, ty = tid >> 4;
    const int le = tid & 63, lg = tid >> 6;
    float acc[4][4] = {};
    for (int d0 = 0; d0 < DIM_; d0 += 16) {
      {
        const float4 v = *(const float4*)&proj_w[(size_t)(et + le) * DIM_ + d0 + lg * 4];
        Pt[(lg * 4 + 0) * 68 + le] = v.x;
        Pt[(lg * 4 + 1) * 68 + le] = v.y;
        Pt[(lg * 4 + 2) * 68 + le] = v.z;
        Pt[(lg * 4 + 3) * 68 + le] = v.w;
      }
#pragma unroll
      for (int r = 0; r < 4; ++r) {
        const int dl = r * 4 + lg;
        Wt[dl * 68 + le] = conv_w[(size_t)(d0 + dl) * (DIM_ * 3) + (it + le) * 3 + kk];
      }
      __syncthreads();
#pragma unroll
      for (int dl = 0; dl < 16; ++dl) {
        const float4 pv = *(const float4*)&Pt[dl * 68 + ty * 4];
        const float4 wv = *(const float4*)&Wt[dl * 68 + tx * 4];
        const float pa[4] = {pv.x, pv.y, pv.z, pv.w};
        const float wa[4] = {wv.x, wv.y, wv.z, wv.w};
#pragma unroll
        for (int a = 0; a < 4; ++a)
#pragma unroll
          for (int b = 0; b < 4; ++b) acc[a][b] += pa[a] * wa[b];
      }
      __syncthreads();
    }
#pragma unroll
    for (int a = 0; a < 4; ++a) {
      uint2 pk;
      pk.x = (unsigned int)f2bf(acc[a][0]) | ((unsigned int)f2bf(acc[a][1]) << 16);
      pk.y = (unsigned int)f2bf(acc[a][2]) | ((unsigned int)f2bf(acc[a][3]) << 16);
      *(uint2*)&Mst[(size_t)(kk * DIM_ + et + ty * 4 + a) * DIM_ + it + tx * 4] = pk;
    }
  } else if (bx < 320) {
    const int idx = bx - 192;
    const int e = idx * 4 + (tid >> 6);
    const int j = tid & 63;
    float s = 0.f;
#pragma unroll
    for (int d = j; d < DIM_; d += 64) s += proj_w[(size_t)e * DIM_ + d] * conv_b[d];
#pragma unroll
    for (int off = 32; off > 0; off >>= 1) s += __shfl_down(s, off, 64);
    if (j == 0) Pcb[e] = s;
  } else {
    const int bc = bx - 320;
    const int bb = bc >> 9;
    const int dt = ((bc >> 6) & 7) << 6;
    const int lt = (bc & 63) << 6;
    const int lr  = tid >> 4;
    const int lc4 = (tid & 15) << 2;
#pragma unroll
    for (int r = 0; r < 4; ++r) {
      const int d = r * 16 + lr;
      const float4 v = *(const float4*)&x[((size_t)(bb * DIM_ + dt + d) << 12) + lt + lc4];
      float* row = sm + d * 65 + lc4;
      row[0] = v.x; row[1] = v.y; row[2] = v.z; row[3] = v.w;
    }
    __syncthreads();
#pragma unroll
    for (int rr = 0; rr < 2; ++rr) {
      const int flat = rr * 256 + tid;
      const int l  = flat >> 3;
      const int d8 = (flat & 7) << 3;
      unsigned int w[4];
#pragma unroll
      for (int p = 0; p < 4; ++p) {
        const float f0 = sm[(d8 + 2 * p + 0) * 65 + l];
        const float f1 = sm[(d8 + 2 * p + 1) * 65 + l];
        w[p] = (unsigned int)f2bf(f0) | ((unsigned int)f2bf(f1) << 16);
      }
      uint4 pk; pk.x = w[0]; pk.y = w[1]; pk.z = w[2]; pk.w = w[3];
      *(uint4*)&Xbt[((size_t)(bb * LIN_ + lt + l) << 9) + dt + d8] = pk;
    }
  }
}

// ---------------------------------------------------------------------------
// 2) k_fused — GEMM + AA filter + both biases, out written directly.
//    Per block: M=192 (3 kk x 64 e), N_out=128 l-cols (N_comp=160 with 16-col
//    halo each side), K=512, BK=32 -> 16 kt.  8 waves (4M x 2N), wave tile
//    48x80 = 3x5 frags, 15 MFMA/kt.
//    LDS: 3-deep ring of 24KB slots (A 12K + B 10K + 2K pad) = 72KB ->
//    2 blocks/CU (the round-2 fix: occupancy 8 -> 16 waves/CU).
//    counted vmcnt(6) steady (3 gloads/wave/stage, 2 tiles in flight);
//    raw barriers; pre-swizzled gload_lds sources.
//    Epilogue: acc -> LDS U-tile [192][168] bf16 (63KB, unions dead ring),
//    syncthreads, 17-tap AA combine -> out fp32.
__global__ __launch_bounds__(512, 4) void k_fused(const unsigned short* __restrict__ Xbt,
                                                  const unsigned short* __restrict__ Mst,
                                                  const float* __restrict__ Pcb,
                                                  const float* __restrict__ aa,
                                                  const float* __restrict__ proj_b,
                                                  float* __restrict__ out) {
  __shared__ __align__(16) char lds[73728];   // max(ring 72KB, U 63KB)
  const int tid = threadIdx.x;
  const int bid = blockIdx.x;
  // XCD-bijective swizzle (2048 = 8*256). Within one XCD the 8 etiles of an
  // ntile are consecutive -> B panel (160KB) stays L2-hot, then ntile++.
  const int wgs   = (bid & 7) * 256 + (bid >> 3);
  const int etile = wgs & 7;             // 0..7
  const int ntile = wgs >> 3;            // 0..255
  const int bb = ntile >> 5;
  const int L0 = (ntile & 31) << 7;      // output l base (128 per tile)
  const int l0g = L0 - 16;               // first computed column
  const int e0 = etile << 6;

  const int wave = tid >> 6;
  const int lane = tid & 63;

  // ---- staging: 24 units x 1KB per slot; wave w -> units w, w+8, w+16.
  // Units 0-11: A rows m=u*16+rl (m = kk*64+e_local, kk=u>>2);
  // units 12-21: B rows l = l0g + (u-12)*16 + rl (clamped to [0,4095]);
  // units 22,23: dummies (mirror A units 0,1) into the 2KB pad so every wave
  // issues exactly 3 gloads per STAGE -> uniform vmcnt counting.
  const unsigned short* src[3];
  int ldso[3];
  {
    const int rl = lane >> 2;
    const int sl = lane & 3;
    const int ch = sl ^ ((rl >> 1) & 3);        // pre-swizzled source chunk
#pragma unroll
    for (int i = 0; i < 3; ++i) {
      const int u  = wave + 8 * i;
      const int uu = (u >= 22) ? (u - 22) : u;
      const unsigned short* p;
      if (uu < 12) {
        const int kk = uu >> 2;
        const int er = e0 + ((uu & 3) << 4) + rl;
        p = Mst + ((size_t)(kk * 512 + er) << 9);
      } else {
        int labs = l0g + (uu - 12) * 16 + rl;
        labs = labs < 0 ? 0 : (labs > 4095 ? 4095 : labs);
        p = Xbt + ((size_t)(bb * LIN_ + labs) << 9);
      }
      src[i] = p + (ch << 3);
      ldso[i] = u << 10;
    }
  }

#define STAGE_(kt_, buf_)                              \
  do {                                                 \
    char* base_ = lds + (buf_) * 24576;                \
    gload16(src[0] + (kt_) * 32, base_ + ldso[0]);     \
    gload16(src[1] + (kt_) * 32, base_ + ldso[1]);     \
    gload16(src[2] + (kt_) * 32, base_ + ldso[2]);     \
  } while (0)

  const int wm = wave >> 1;              // 0..3 : 48-row M strip
  const int wn = wave & 1;               // 0..1 : 80-col N half
  const int lrow = lane & 15;
  const int lc   = lane >> 4;            // k-chunk 0..3
  const int asl  = lc ^ ((lrow >> 1) & 3);
  const char* A0 = lds + ((wm * 48 + lrow) * 64 + asl * 16);
  const char* B0 = lds + (12288 + (wn * 80 + lrow) * 64 + asl * 16);

  f32x4 acc[3][5] = {};

  STAGE_(0, 0); STAGE_(1, 1);

#pragma unroll
  for (int kt = 0; kt < 16; ++kt) {
    if (kt < 14) {
      STAGE_(kt + 2, (kt + 2) % 3);
      asm volatile("s_waitcnt vmcnt(6)" ::: "memory");
    } else if (kt == 14) {
      asm volatile("s_waitcnt vmcnt(3)" ::: "memory");
    } else {
      asm volatile("s_waitcnt vmcnt(0)" ::: "memory");
    }
    __builtin_amdgcn_s_barrier();
    __builtin_amdgcn_sched_barrier(0);

    const int bo = (kt % 3) * 24576;
    bf16x8 af[3], bfv[5];
#pragma unroll
    for (int mt = 0; mt < 3; ++mt) af[mt] = *(const bf16x8*)(A0 + bo + mt * 1024);
#pragma unroll
    for (int nt = 0; nt < 5; ++nt) bfv[nt] = *(const bf16x8*)(B0 + bo + nt * 1024);
#pragma unroll
    for (int mt = 0; mt < 3; ++mt)
#pragma unroll
      for (int nt = 0; nt < 5; ++nt)
        // swapped operands: D row = l (quad*4+reg), D col = m (lane&15)
        acc[mt][nt] = __builtin_amdgcn_mfma_f32_16x16x32_bf16(bfv[nt], af[mt],
                                                              acc[mt][nt], 0, 0, 0);
    asm volatile("s_waitcnt lgkmcnt(0)" ::: "memory");
    __builtin_amdgcn_sched_barrier(0);
    __builtin_amdgcn_s_barrier();
  }
#undef STAGE_

  // ---- epilogue A: acc -> LDS U-tile (bf16, [192][168]; unions dead ring) ----
  unsigned short* Ut = (unsigned short*)lds;
#pragma unroll
  for (int mt = 0; mt < 3; ++mt) {
    const int m = wm * 48 + mt * 16 + lrow;          // m = kk*64 + e_local
#pragma unroll
    for (int nt = 0; nt < 5; ++nt) {
      const int lcol = wn * 80 + nt * 16 + (lc << 2);
      uint2 pk;
      pk.x = (unsigned int)f2bf(acc[mt][nt][0]) | ((unsigned int)f2bf(acc[mt][nt][1]) << 16);
      pk.y = (unsigned int)f2bf(acc[mt][nt][2]) | ((unsigned int)f2bf(acc[mt][nt][3]) << 16);
      *(uint2*)&Ut[m * 168 + lcol] = pk;
    }
  }
  __syncthreads();

  // ---- epilogue B: AA combine + biases, store out ----
  // thread t: e_local = t>>3, seg = t&7 -> 16 input l, 32 output samples.
  const int el  = tid >> 3;
  const int seg = tid & 7;
  const int lt0 = seg << 4;
  const int e   = e0 + el;
  const float pcb = Pcb[e];
  const float pb  = proj_b[e];
  float sa[17];
#pragma unroll
  for (int j = 0; j < 17; ++j) sa[j] = aa[j];
  const unsigned short* u0r = Ut + (size_t)el * 168;          // kk=0
  const unsigned short* u1r = Ut + (size_t)(64 + el) * 168;   // kk=1
  const unsigned short* u2r = Ut + (size_t)(128 + el) * 168;  // kk=2
  const int P0 = L0 + lt0;                                    // first input l
  const bool edge = (L0 == 0 && seg == 0) || (L0 == 3968 && seg == 7);

  float E[25], O[24];
  if (!edge) {
    // interior: aligned 16B window cols [lt0+8, lt0+40) covers [c0-4, c0+21)
    u16x8 w1[4], w0[4], w2[4];
#pragma unroll
    for (int c = 0; c < 4; ++c) {
      w1[c] = *(const u16x8*)(u1r + lt0 + 8 + 8 * c);
      w0[c] = *(const u16x8*)(u0r + lt0 + 8 + 8 * c);
      w2[c] = *(const u16x8*)(u2r + lt0 + 8 + 8 * c);
    }
#pragma unroll
    for (int j = 0; j < 25; ++j)
      E[j] = bf2f(w1[(j + 4) >> 3][(j + 4) & 7]) + pcb;
#pragma unroll
    for (int j = 0; j < 24; ++j)
      O[j] = bf2f(w0[(j + 4) >> 3][(j + 4) & 7]) + pcb +
             bf2f(w2[(j + 5) >> 3][(j + 5) & 7]);
  } else {
#pragma unroll
    for (int j = 0; j < 25; ++j) {
      const int l = P0 - 4 + j;
      const int c = lt0 + 12 + j;
      E[j] = (l >= 0 && l < 4096) ? (bf2f(u1r[c]) + pcb) : 0.f;
    }
#pragma unroll
    for (int j = 0; j < 24; ++j) {
      const int l = P0 - 4 + j;
      const int c = lt0 + 12 + j;
      float v = 0.f;
      if (l >= 0 && l < 4096) {
        v = bf2f(u0r[c]) + pcb;
        if (l + 1 < 4096) v += bf2f(u2r[c + 1]);
      }
      O[j] = v;
    }
  }

  float* orow = out + (((size_t)(bb * 512 + e)) << 13) + 2 * (size_t)P0;
#pragma unroll
  for (int t2 = 0; t2 < 8; ++t2) {       // two input positions per iteration
    float r4[4];
#pragma unroll
    for (int h = 0; h < 2; ++h) {
      const int t = 2 * t2 + h;
      float se = 0.f, so = 0.f;
#pragma unroll
      for (int q = 0; q <= 8; ++q) {     // even taps
        se += sa[2 * q] * E[t + q];
        so += sa[2 * q] * O[t + q];
      }
#pragma unroll
      for (int q = 0; q < 8; ++q) {      // odd taps
        se += sa[2 * q + 1] * O[t + q];
        so += sa[2 * q + 1] * E[t + q + 1];
      }
      r4[2 * h]     = se + pb;
      r4[2 * h + 1] = so + pb;
    }
    *(float4*)(orow + 4 * t2) = *(const float4*)r4;
  }
}

// ---------------------------------------------------------------------------
extern "C" void kernel_launch(void* const* d_in, const int* in_sizes, int n_in,
                              void* d_out, int out_size, void* d_ws, size_t ws_size,
                              hipStream_t stream) {
  const float* x      = (const float*)d_in[0];
  const float* conv_w = (const float*)d_in[1];
  const float* conv_b = (const float*)d_in[2];
  const float* aa     = (const float*)d_in[3];
  const float* proj_w = (const float*)d_in[4];
  const float* proj_b = (const float*)d_in[5];
  float* out = (float*)d_out;

  char* ws = (char*)d_ws;
  unsigned short* Mst = (unsigned short*)ws;              //  1,572,864 B
  float*          Pcb = (float*)(ws + 1572864);           //      2,048 B
  unsigned short* Xbt = (unsigned short*)(ws + 1574912);  // 33,554,432 B (tot 35.1MB)

  k_prep<<<dim3(4416, 1, 1), 256, 0, stream>>>(proj_w, conv_w, conv_b, x, Mst, Pcb, Xbt);
  k_fused<<<dim3(2048, 1, 1), 512, 0, stream>>>(Xbt, Mst, Pcb, aa, proj_b, out);
}

// Round 4
// 321.998 us; speedup vs baseline: 1.0190x; 1.0190x over previous
//
#include <hip/hip_runtime.h>
#include <hip/hip_bf16.h>

// Problem constants
#define BB_   8
#define DIM_  512
#define LIN_  4096
#define LOUT_ 8192

typedef __attribute__((ext_vector_type(8))) __bf16 bf16x8;
typedef __attribute__((ext_vector_type(4))) float  f32x4;
typedef __attribute__((ext_vector_type(8))) unsigned short u16x8;

__device__ __forceinline__ float bf2f(unsigned short u) {
  union { unsigned int i; float f; } x;
  x.i = ((unsigned int)u) << 16;
  return x.f;
}

// RNE float->bf16
__device__ __forceinline__ unsigned short f2bf(float f) {
  unsigned int u = __float_as_uint(f);
  return (unsigned short)((u + 0x7fffu + ((u >> 16) & 1u)) >> 16);
}

// async global->LDS, 16B per lane; LDS dest = wave-uniform base + lane*16
__device__ __forceinline__ void gload16(const void* g, void* l) {
  __builtin_amdgcn_global_load_lds(
      (__attribute__((address_space(1))) void*)(g),
      (__attribute__((address_space(3))) void*)(l), 16, 0, 0);
}

// ---------------------------------------------------------------------------
// 1) k_prep — heterogeneous grid, 4416 blocks (unchanged):
//    [0,192):    Mst[kk*512+e][i] = sum_d proj_w[e,d]*conv_w[d,i,kk]  (bf16)
//    [192,320):  Pcb[e] = sum_d proj_w[e,d]*conv_b[d]
//    [320,4416): Xbt[b][l][d] = bf16(x[b][d][l])
__global__ __launch_bounds__(256) void k_prep(const float* __restrict__ proj_w,
                                              const float* __restrict__ conv_w,
                                              const float* __restrict__ conv_b,
                                              const float* __restrict__ x,
                                              unsigned short* __restrict__ Mst,
                                              float* __restrict__ Pcb,
                                              unsigned short* __restrict__ Xbt) {
  __shared__ __align__(16) float sm[4160];
  const int bx  = blockIdx.x;
  const int tid = threadIdx.x;

  if (bx < 192) {
    float* Pt = sm;           // [16][68]
    float* Wt = sm + 1088;    // [16][68]
    const int kk = bx >> 6;
    const int t6 = bx & 63;
    const int et = (t6 >> 3) << 6;
    const int it = (t6 & 7) << 6;
    const int tx = tid & 15, ty = tid >> 4;
    const int le = tid & 63, lg = tid >> 6;
    float acc[4][4] = {};
    for (int d0 = 0; d0 < DIM_; d0 += 16) {
      {
        const float4 v = *(const float4*)&proj_w[(size_t)(et + le) * DIM_ + d0 + lg * 4];
        Pt[(lg * 4 + 0) * 68 + le] = v.x;
        Pt[(lg * 4 + 1) * 68 + le] = v.y;
        Pt[(lg * 4 + 2) * 68 + le] = v.z;
        Pt[(lg * 4 + 3) * 68 + le] = v.w;
      }
#pragma unroll
      for (int r = 0; r < 4; ++r) {
        const int dl = r * 4 + lg;
        Wt[dl * 68 + le] = conv_w[(size_t)(d0 + dl) * (DIM_ * 3) + (it + le) * 3 + kk];
      }
      __syncthreads();
#pragma unroll
      for (int dl = 0; dl < 16; ++dl) {
        const float4 pv = *(const float4*)&Pt[dl * 68 + ty * 4];
        const float4 wv = *(const float4*)&Wt[dl * 68 + tx * 4];
        const float pa[4] = {pv.x, pv.y, pv.z, pv.w};
        const float wa[4] = {wv.x, wv.y, wv.z, wv.w};
#pragma unroll
        for (int a = 0; a < 4; ++a)
#pragma unroll
          for (int b = 0; b < 4; ++b) acc[a][b] += pa[a] * wa[b];
      }
      __syncthreads();
    }
#pragma unroll
    for (int a = 0; a < 4; ++a) {
      uint2 pk;
      pk.x = (unsigned int)f2bf(acc[a][0]) | ((unsigned int)f2bf(acc[a][1]) << 16);
      pk.y = (unsigned int)f2bf(acc[a][2]) | ((unsigned int)f2bf(acc[a][3]) << 16);
      *(uint2*)&Mst[(size_t)(kk * DIM_ + et + ty * 4 + a) * DIM_ + it + tx * 4] = pk;
    }
  } else if (bx < 320) {
    const int idx = bx - 192;
    const int e = idx * 4 + (tid >> 6);
    const int j = tid & 63;
    float s = 0.f;
#pragma unroll
    for (int d = j; d < DIM_; d += 64) s += proj_w[(size_t)e * DIM_ + d] * conv_b[d];
#pragma unroll
    for (int off = 32; off > 0; off >>= 1) s += __shfl_down(s, off, 64);
    if (j == 0) Pcb[e] = s;
  } else {
    const int bc = bx - 320;
    const int bb = bc >> 9;
    const int dt = ((bc >> 6) & 7) << 6;
    const int lt = (bc & 63) << 6;
    const int lr  = tid >> 4;
    const int lc4 = (tid & 15) << 2;
#pragma unroll
    for (int r = 0; r < 4; ++r) {
      const int d = r * 16 + lr;
      const float4 v = *(const float4*)&x[((size_t)(bb * DIM_ + dt + d) << 12) + lt + lc4];
      float* row = sm + d * 65 + lc4;
      row[0] = v.x; row[1] = v.y; row[2] = v.z; row[3] = v.w;
    }
    __syncthreads();
#pragma unroll
    for (int rr = 0; rr < 2; ++rr) {
      const int flat = rr * 256 + tid;
      const int l  = flat >> 3;
      const int d8 = (flat & 7) << 3;
      unsigned int w[4];
#pragma unroll
      for (int p = 0; p < 4; ++p) {
        const float f0 = sm[(d8 + 2 * p + 0) * 65 + l];
        const float f1 = sm[(d8 + 2 * p + 1) * 65 + l];
        w[p] = (unsigned int)f2bf(f0) | ((unsigned int)f2bf(f1) << 16);
      }
      uint4 pk; pk.x = w[0]; pk.y = w[1]; pk.z = w[2]; pk.w = w[3];
      *(uint4*)&Xbt[((size_t)(bb * LIN_ + lt + l) << 9) + dt + d8] = pk;
    }
  }
}

// ---------------------------------------------------------------------------
// 2) k_fused — GEMM + AA filter + both biases, out written directly.
//    Per block: M=192 (3 kk x 64 e), N_out=256 (N_comp=288 with 16-col halo
//    each side), K=512, BK=32 -> 16 bodies.  8 waves 4M x 2N, wave tile
//    48x144 = 3x9 frags, 27 MFMA/body.
//    ROUND-4 RESTRUCTURE (2-phase ceiling fix): cross-barrier register
//    prefetch.  Body kt: STAGE(kt+2) -> vmcnt(4) -> s_barrier -> ds_read
//    regs[kt+1] from buf (kt+1)%4 -> setprio(1) -> 27 MFMA on regs[kt]
//    (operands already in VGPRs: no LDS latency at cluster top) -> setprio(0).
//    ONE barrier per body, no lgkmcnt(0) drain.  Ring R=4 x 32KB, prefetch
//    P=2: staged slot (kt+2)%4 disjoint from possibly-pending-read slots
//    {kt-1,kt,kt+1}%4 (waves <=1 barrier apart) -- P=3 would race.
//    Epilogue: post-loop barrier, acc -> LDS U-tile [192][296] bf16 (113.6KB,
//    unions dead ring), syncthreads, 17-tap AA combine -> out fp32.
__global__ __launch_bounds__(512, 1) void k_fused(const unsigned short* __restrict__ Xbt,
                                                  const unsigned short* __restrict__ Mst,
                                                  const float* __restrict__ Pcb,
                                                  const float* __restrict__ aa,
                                                  const float* __restrict__ proj_b,
                                                  float* __restrict__ out) {
  __shared__ __align__(16) char lds[131072];
  const int tid = threadIdx.x;
  const int bid = blockIdx.x;
  // XCD-bijective swizzle (1024 = 8*128); one XCD: 16 ntiles x 8 etiles.
  const int wgs   = (bid & 7) * 128 + (bid >> 3);
  const int ntile = wgs >> 3;            // 0..127
  const int etile = wgs & 7;             // 0..7
  const int bb = ntile >> 4;
  const int L0 = (ntile & 15) << 8;      // output l base (256 per tile)
  const int l0g = L0 - 16;               // first computed column
  const int e0 = etile << 6;

  const int wave = tid >> 6;
  const int lane = tid & 63;

  // ---- staging: 32 units x 1KB per slot; wave w -> units w, w+8, w+16, w+24.
  // Units 0-11: A rows m=uu*16+rl (m = kk*64+e_local, kk=uu>>2); 12-29: B rows
  // l = l0g + (uu-12)*16 + rl (clamped to [0,4095], edges masked later);
  // 30,31: dummies (mirror A units 0,1) into the 2KB pad -> every wave issues
  // exactly 4 gloads per STAGE -> uniform vmcnt counting.
  const unsigned short* src[4];
  int ldso[4];
  {
    const int rl = lane >> 2;
    const int sl = lane & 3;
    const int ch = sl ^ ((rl >> 1) & 3);          // pre-swizzled source chunk
#pragma unroll
    for (int i = 0; i < 4; ++i) {
      const int u  = wave + 8 * i;
      const int uu = (u >= 30) ? (u - 30) : u;
      const unsigned short* p;
      if (uu < 12) {
        const int kk = uu >> 2;
        const int er = e0 + ((uu & 3) << 4) + rl;
        p = Mst + ((size_t)(kk * 512 + er) << 9);
      } else {
        int labs = l0g + (uu - 12) * 16 + rl;
        labs = labs < 0 ? 0 : (labs > 4095 ? 4095 : labs);
        p = Xbt + ((size_t)(bb * LIN_ + labs) << 9);
      }
      src[i] = p + (ch << 3);
      ldso[i] = u << 10;
    }
  }

#define STAGE_(kt_, buf_)                              \
  do {                                                 \
    char* base_ = lds + (buf_) * 32768;                \
    gload16(src[0] + (kt_) * 32, base_ + ldso[0]);     \
    gload16(src[1] + (kt_) * 32, base_ + ldso[1]);     \
    gload16(src[2] + (kt_) * 32, base_ + ldso[2]);     \
    gload16(src[3] + (kt_) * 32, base_ + ldso[3]);     \
  } while (0)

  const int wm = wave >> 1;              // 0..3 : 48-row M strip
  const int wn = wave & 1;               // 0..1 : 144-col N half
  const int lrow = lane & 15;
  const int lc   = lane >> 4;            // k-chunk 0..3
  const int asl  = lc ^ ((lrow >> 1) & 3);
  const char* A0 = lds + ((wm * 48 + lrow) * 64 + asl * 16);
  const char* B0 = lds + (12288 + (wn * 144 + lrow) * 64 + asl * 16);

  f32x4 acc[3][9] = {};
  bf16x8 afr[2][3], bfr[2][9];

  // ---- prologue: fill bufs 0,1; load regs[0] from buf 0 ----
  STAGE_(0, 0); STAGE_(1, 1);
  asm volatile("s_waitcnt vmcnt(4)" ::: "memory");
  __builtin_amdgcn_s_barrier();
  __builtin_amdgcn_sched_barrier(0);
#pragma unroll
  for (int mt = 0; mt < 3; ++mt) afr[0][mt] = *(const bf16x8*)(A0 + mt * 1024);
#pragma unroll
  for (int nt = 0; nt < 9; ++nt) bfr[0][nt] = *(const bf16x8*)(B0 + nt * 1024);

#pragma unroll
  for (int kt = 0; kt < 16; ++kt) {
    const int cur = kt & 1, nxt = cur ^ 1;       // compile-time (full unroll)
    if (kt < 14) {
      STAGE_(kt + 2, (kt + 2) & 3);
      asm volatile("s_waitcnt vmcnt(4)" ::: "memory");
    } else {
      asm volatile("s_waitcnt vmcnt(0)" ::: "memory");
    }
    __builtin_amdgcn_s_barrier();
    __builtin_amdgcn_sched_barrier(0);

    if (kt < 15) {                               // prefetch regs[kt+1]
      const int bo = ((kt + 1) & 3) * 32768;
#pragma unroll
      for (int mt = 0; mt < 3; ++mt)
        afr[nxt][mt] = *(const bf16x8*)(A0 + bo + mt * 1024);
#pragma unroll
      for (int nt = 0; nt < 9; ++nt)
        bfr[nxt][nt] = *(const bf16x8*)(B0 + bo + nt * 1024);
    }

    __builtin_amdgcn_s_setprio(1);
#pragma unroll
    for (int mt = 0; mt < 3; ++mt)
#pragma unroll
      for (int nt = 0; nt < 9; ++nt)
        // swapped operands: D row = l (quad*4+reg), D col = m (lane&15)
        acc[mt][nt] = __builtin_amdgcn_mfma_f32_16x16x32_bf16(bfr[cur][nt],
                                                              afr[cur][mt],
                                                              acc[mt][nt], 0, 0, 0);
    __builtin_amdgcn_s_setprio(0);
  }
#undef STAGE_
  __builtin_amdgcn_s_barrier();   // all pending LDS reads consumed before Ut writes

  // ---- epilogue A: acc -> LDS U-tile (bf16, stride 296; unions dead ring) ----
  unsigned short* Ut = (unsigned short*)lds;
#pragma unroll
  for (int mt = 0; mt < 3; ++mt) {
    const int m = wm * 48 + mt * 16 + lrow;          // m = kk*64 + e_local
#pragma unroll
    for (int nt = 0; nt < 9; ++nt) {
      const int lcol = wn * 144 + nt * 16 + (lc << 2);
      uint2 pk;
      pk.x = (unsigned int)f2bf(acc[mt][nt][0]) | ((unsigned int)f2bf(acc[mt][nt][1]) << 16);
      pk.y = (unsigned int)f2bf(acc[mt][nt][2]) | ((unsigned int)f2bf(acc[mt][nt][3]) << 16);
      *(uint2*)&Ut[m * 296 + lcol] = pk;
    }
  }
  __syncthreads();

  // ---- epilogue B: AA combine + biases, store out ----
  // thread t: e_local = t>>3, l-chunk base = (t&7)*32 (thread owns a 256B strip)
  const int el  = tid >> 3;
  const int lt0 = (tid & 7) << 5;
  const int e   = e0 + el;
  const float pcb = Pcb[e];
  const float pb  = proj_b[e];
  float sa[17];
#pragma unroll
  for (int j = 0; j < 17; ++j) sa[j] = aa[j];
  const unsigned short* u0r = Ut + (size_t)el * 296;          // kk=0
  const unsigned short* u1r = Ut + (size_t)(64 + el) * 296;   // kk=1
  const unsigned short* u2r = Ut + (size_t)(128 + el) * 296;  // kk=2
  const bool edge = (L0 == 0) || (L0 == 3840);
  float* orow = out + (((size_t)(bb * 512 + e)) << 13) + 2 * (size_t)(L0 + lt0);

#pragma unroll
  for (int cc = 0; cc < 4; ++cc) {
    const int c0 = lt0 + 8 * cc + 12;   // Ut col of E[0]  (c = l - l0g = c0 + j)
    float E[17], O[16];
    if (!edge) {
      // interior: aligned 16B window [c0-4, c0+20) covers all needed cols
      const u16x8 e0v = *(const u16x8*)(u1r + c0 - 4);
      const u16x8 e1v = *(const u16x8*)(u1r + c0 + 4);
      const u16x8 e2v = *(const u16x8*)(u1r + c0 + 12);
      const u16x8 a0v = *(const u16x8*)(u0r + c0 - 4);
      const u16x8 a1v = *(const u16x8*)(u0r + c0 + 4);
      const u16x8 a2v = *(const u16x8*)(u0r + c0 + 12);
      const u16x8 b0v = *(const u16x8*)(u2r + c0 - 4);
      const u16x8 b1v = *(const u16x8*)(u2r + c0 + 4);
      const u16x8 b2v = *(const u16x8*)(u2r + c0 + 12);
      unsigned short ue[24], ua[24], ub[24];
#pragma unroll
      for (int j = 0; j < 8; ++j) {
        ue[j] = e0v[j]; ue[j + 8] = e1v[j]; ue[j + 16] = e2v[j];
        ua[j] = a0v[j]; ua[j + 8] = a1v[j]; ua[j + 16] = a2v[j];
        ub[j] = b0v[j]; ub[j + 8] = b1v[j]; ub[j + 16] = b2v[j];
      }
#pragma unroll
      for (int j = 0; j < 17; ++j) E[j] = bf2f(ue[4 + j]) + pcb;
#pragma unroll
      for (int j = 0; j < 16; ++j) O[j] = bf2f(ua[4 + j]) + pcb + bf2f(ub[5 + j]);
    } else {
      const int lt = L0 + lt0 + 8 * cc;
#pragma unroll
      for (int j = 0; j < 17; ++j) {
        const int l = lt - 4 + j;
        E[j] = (l >= 0 && l < 4096) ? (bf2f(u1r[c0 + j]) + pcb) : 0.f;
      }
#pragma unroll
      for (int j = 0; j < 16; ++j) {
        const int l = lt - 4 + j;
        float v = 0.f;
        if (l >= 0 && l < 4096) {
          v = bf2f(u0r[c0 + j]) + pcb;
          if (l + 1 < 4096) v += bf2f(u2r[c0 + j + 1]);
        }
        O[j] = v;
      }
    }
    float res[16];
#pragma unroll
    for (int t = 0; t < 8; ++t) {
      float se = 0.f, so = 0.f;
#pragma unroll
      for (int q = 0; q <= 8; ++q) {   // even taps
        se += sa[2 * q] * E[t + q];
        so += sa[2 * q] * O[t + q];
      }
#pragma unroll
      for (int q = 0; q < 8; ++q) {    // odd taps
        se += sa[2 * q + 1] * O[t + q];
        so += sa[2 * q + 1] * E[t + q + 1];
      }
      res[2 * t]     = se + pb;
      res[2 * t + 1] = so + pb;
    }
#pragma unroll
    for (int c2 = 0; c2 < 4; ++c2)
      *(float4*)(orow + 16 * cc + 4 * c2) = *(const float4*)&res[4 * c2];
  }
}

// ---------------------------------------------------------------------------
extern "C" void kernel_launch(void* const* d_in, const int* in_sizes, int n_in,
                              void* d_out, int out_size, void* d_ws, size_t ws_size,
                              hipStream_t stream) {
  const float* x      = (const float*)d_in[0];
  const float* conv_w = (const float*)d_in[1];
  const float* conv_b = (const float*)d_in[2];
  const float* aa     = (const float*)d_in[3];
  const float* proj_w = (const float*)d_in[4];
  const float* proj_b = (const float*)d_in[5];
  float* out = (float*)d_out;

  char* ws = (char*)d_ws;
  unsigned short* Mst = (unsigned short*)ws;              //  1,572,864 B
  float*          Pcb = (float*)(ws + 1572864);           //      2,048 B
  unsigned short* Xbt = (unsigned short*)(ws + 1574912);  // 33,554,432 B (tot 35.1MB)

  k_prep<<<dim3(4416, 1, 1), 256, 0, stream>>>(proj_w, conv_w, conv_b, x, Mst, Pcb, Xbt);
  k_fused<<<dim3(1024, 1, 1), 512, 0, stream>>>(Xbt, Mst, Pcb, aa, proj_b, out);
}

// Round 6
// 317.613 us; speedup vs baseline: 1.0331x; 1.0138x over previous
//
#include <hip/hip_runtime.h>
#include <hip/hip_bf16.h>

// Problem constants
#define BB_   8
#define DIM_  512
#define LIN_  4096
#define LOUT_ 8192

typedef __attribute__((ext_vector_type(8))) __bf16 bf16x8;
typedef __attribute__((ext_vector_type(4))) float  f32x4;
typedef __attribute__((ext_vector_type(8))) unsigned short u16x8;

__device__ __forceinline__ float bf2f(unsigned short u) {
  union { unsigned int i; float f; } x;
  x.i = ((unsigned int)u) << 16;
  return x.f;
}

// RNE float->bf16
__device__ __forceinline__ unsigned short f2bf(float f) {
  unsigned int u = __float_as_uint(f);
  return (unsigned short)((u + 0x7fffu + ((u >> 16) & 1u)) >> 16);
}

// async global->LDS, 16B per lane; LDS dest = wave-uniform base + lane*16
__device__ __forceinline__ void gload16(const void* g, void* l) {
  __builtin_amdgcn_global_load_lds(
      (__attribute__((address_space(1))) void*)(g),
      (__attribute__((address_space(3))) void*)(l), 16, 0, 0);
}

// ---------------------------------------------------------------------------
// 1) k_prep — heterogeneous grid, 4416 blocks (unchanged):
//    [0,192):    Mst[kk*512+e][i] = sum_d proj_w[e,d]*conv_w[d,i,kk]  (bf16)
//    [192,320):  Pcb[e] = sum_d proj_w[e,d]*conv_b[d]
//    [320,4416): Xbt[b][l][d] = bf16(x[b][d][l])
__global__ __launch_bounds__(256) void k_prep(const float* __restrict__ proj_w,
                                              const float* __restrict__ conv_w,
                                              const float* __restrict__ conv_b,
                                              const float* __restrict__ x,
                                              unsigned short* __restrict__ Mst,
                                              float* __restrict__ Pcb,
                                              unsigned short* __restrict__ Xbt) {
  __shared__ __align__(16) float sm[4160];
  const int bx  = blockIdx.x;
  const int tid = threadIdx.x;

  if (bx < 192) {
    float* Pt = sm;           // [16][68]
    float* Wt = sm + 1088;    // [16][68]
    const int kk = bx >> 6;
    const int t6 = bx & 63;
    const int et = (t6 >> 3) << 6;
    const int it = (t6 & 7) << 6;
    const int tx = tid & 15, ty = tid >> 4;
    const int le = tid & 63, lg = tid >> 6;
    float acc[4][4] = {};
    for (int d0 = 0; d0 < DIM_; d0 += 16) {
      {
        const float4 v = *(const float4*)&proj_w[(size_t)(et + le) * DIM_ + d0 + lg * 4];
        Pt[(lg * 4 + 0) * 68 + le] = v.x;
        Pt[(lg * 4 + 1) * 68 + le] = v.y;
        Pt[(lg * 4 + 2) * 68 + le] = v.z;
        Pt[(lg * 4 + 3) * 68 + le] = v.w;
      }
#pragma unroll
      for (int r = 0; r < 4; ++r) {
        const int dl = r * 4 + lg;
        Wt[dl * 68 + le] = conv_w[(size_t)(d0 + dl) * (DIM_ * 3) + (it + le) * 3 + kk];
      }
      __syncthreads();
#pragma unroll
      for (int dl = 0; dl < 16; ++dl) {
        const float4 pv = *(const float4*)&Pt[dl * 68 + ty * 4];
        const float4 wv = *(const float4*)&Wt[dl * 68 + tx * 4];
        const float pa[4] = {pv.x, pv.y, pv.z, pv.w};
        const float wa[4] = {wv.x, wv.y, wv.z, wv.w};
#pragma unroll
        for (int a = 0; a < 4; ++a)
#pragma unroll
          for (int b = 0; b < 4; ++b) acc[a][b] += pa[a] * wa[b];
      }
      __syncthreads();
    }
#pragma unroll
    for (int a = 0; a < 4; ++a) {
      uint2 pk;
      pk.x = (unsigned int)f2bf(acc[a][0]) | ((unsigned int)f2bf(acc[a][1]) << 16);
      pk.y = (unsigned int)f2bf(acc[a][2]) | ((unsigned int)f2bf(acc[a][3]) << 16);
      *(uint2*)&Mst[(size_t)(kk * DIM_ + et + ty * 4 + a) * DIM_ + it + tx * 4] = pk;
    }
  } else if (bx < 320) {
    const int idx = bx - 192;
    const int e = idx * 4 + (tid >> 6);
    const int j = tid & 63;
    float s = 0.f;
#pragma unroll
    for (int d = j; d < DIM_; d += 64) s += proj_w[(size_t)e * DIM_ + d] * conv_b[d];
#pragma unroll
    for (int off = 32; off > 0; off >>= 1) s += __shfl_down(s, off, 64);
    if (j == 0) Pcb[e] = s;
  } else {
    const int bc = bx - 320;
    const int bb = bc >> 9;
    const int dt = ((bc >> 6) & 7) << 6;
    const int lt = (bc & 63) << 6;
    const int lr  = tid >> 4;
    const int lc4 = (tid & 15) << 2;
#pragma unroll
    for (int r = 0; r < 4; ++r) {
      const int d = r * 16 + lr;
      const float4 v = *(const float4*)&x[((size_t)(bb * DIM_ + dt + d) << 12) + lt + lc4];
      float* row = sm + d * 65 + lc4;
      row[0] = v.x; row[1] = v.y; row[2] = v.z; row[3] = v.w;
    }
    __syncthreads();
#pragma unroll
    for (int rr = 0; rr < 2; ++rr) {
      const int flat = rr * 256 + tid;
      const int l  = flat >> 3;
      const int d8 = (flat & 7) << 3;
      unsigned int w[4];
#pragma unroll
      for (int p = 0; p < 4; ++p) {
        const float f0 = sm[(d8 + 2 * p + 0) * 65 + l];
        const float f1 = sm[(d8 + 2 * p + 1) * 65 + l];
        w[p] = (unsigned int)f2bf(f0) | ((unsigned int)f2bf(f1) << 16);
      }
      uint4 pk; pk.x = w[0]; pk.y = w[1]; pk.z = w[2]; pk.w = w[3];
      *(uint4*)&Xbt[((size_t)(bb * LIN_ + lt + l) << 9) + dt + d8] = pk;
    }
  }
}

// ---------------------------------------------------------------------------
// 2) k_fused — GEMM + AA filter + both biases, out written directly.
//    Per block: M=192 (3 kk x 64 e), N_out=256 (N_comp=288 with 16-col halo
//    each side), K=512, BK=32 -> 16 bodies.  8 waves 4M x 2N, wave tile
//    48x144 = 3x9 frags, 27 MFMA/body.
//    ROUND-6 (race-fixed round-5 rhythm): body kt =
//      phase A: ds_read af0..2+bf0..3 (7 b128) of buf[kt] | STAGE_A(kt+2) |
//               barrier | lgkmcnt(0) | setprio1 | 12 MFMA | setprio0
//      phase B: ds_read bf4..8 (5 b128) | STAGE_B(kt+2) | barrier |
//               lgkmcnt(0) | setprio1 | 15 MFMA | setprio0
//      end:     vmcnt(4) | barrier      <- retires buf[kt+1] for EVERY wave
//                                          one barrier before its reads.
//    Invariant (race-free): after end-of-body-kt wait, outstanding per wave =
//    exactly body kt's own 4 gloads (buf[kt+2]).  Drain: vmcnt(0) at kt=14.
//    WAR: 3 barriers/body keep waves within one phase; reads {kt,kt+1} vs
//    in-flight writes {kt+2} disjoint in the R=4 x 32KB ring.
//    Epilogue: acc -> LDS U-tile [192][296] bf16 (113.6KB, unions dead ring),
//    syncthreads, 17-tap AA combine -> out fp32.  (identical to round 4)
__global__ __launch_bounds__(512, 1) void k_fused(const unsigned short* __restrict__ Xbt,
                                                  const unsigned short* __restrict__ Mst,
                                                  const float* __restrict__ Pcb,
                                                  const float* __restrict__ aa,
                                                  const float* __restrict__ proj_b,
                                                  float* __restrict__ out) {
  __shared__ __align__(16) char lds[131072];
  const int tid = threadIdx.x;
  const int bid = blockIdx.x;
  // XCD-bijective swizzle (1024 = 8*128); one XCD: 16 ntiles x 8 etiles.
  const int wgs   = (bid & 7) * 128 + (bid >> 3);
  const int ntile = wgs >> 3;            // 0..127
  const int etile = wgs & 7;             // 0..7
  const int bb = ntile >> 4;
  const int L0 = (ntile & 15) << 8;      // output l base (256 per tile)
  const int l0g = L0 - 16;               // first computed column
  const int e0 = etile << 6;

  const int wave = tid >> 6;
  const int lane = tid & 63;

  // ---- staging: 32 units x 1KB per slot; wave w -> units w, w+8, w+16, w+24.
  // Units 0-11: A rows m=uu*16+rl (m = kk*64+e_local, kk=uu>>2); 12-29: B rows
  // l = l0g + (uu-12)*16 + rl (clamped to [0,4095], edges masked later);
  // 30,31: dummies (mirror A units 0,1) into the 2KB pad -> every wave issues
  // exactly 4 gloads per body (2 per phase) -> uniform vmcnt counting.
  const unsigned short* src[4];
  int ldso[4];
  {
    const int rl = lane >> 2;
    const int sl = lane & 3;
    const int ch = sl ^ ((rl >> 1) & 3);          // pre-swizzled source chunk
#pragma unroll
    for (int i = 0; i < 4; ++i) {
      const int u  = wave + 8 * i;
      const int uu = (u >= 30) ? (u - 30) : u;
      const unsigned short* p;
      if (uu < 12) {
        const int kk = uu >> 2;
        const int er = e0 + ((uu & 3) << 4) + rl;
        p = Mst + ((size_t)(kk * 512 + er) << 9);
      } else {
        int labs = l0g + (uu - 12) * 16 + rl;
        labs = labs < 0 ? 0 : (labs > 4095 ? 4095 : labs);
        p = Xbt + ((size_t)(bb * LIN_ + labs) << 9);
      }
      src[i] = p + (ch << 3);
      ldso[i] = u << 10;
    }
  }

#define STAGE2A_(kt_, buf_)                            \
  do {                                                 \
    char* base_ = lds + (buf_) * 32768;                \
    gload16(src[0] + (kt_) * 32, base_ + ldso[0]);     \
    gload16(src[1] + (kt_) * 32, base_ + ldso[1]);     \
  } while (0)
#define STAGE2B_(kt_, buf_)                            \
  do {                                                 \
    char* base_ = lds + (buf_) * 32768;                \
    gload16(src[2] + (kt_) * 32, base_ + ldso[2]);     \
    gload16(src[3] + (kt_) * 32, base_ + ldso[3]);     \
  } while (0)

  const int wm = wave >> 1;              // 0..3 : 48-row M strip
  const int wn = wave & 1;               // 0..1 : 144-col N half
  const int lrow = lane & 15;
  const int lc   = lane >> 4;            // k-chunk 0..3
  const int asl  = lc ^ ((lrow >> 1) & 3);
  const char* A0 = lds + ((wm * 48 + lrow) * 64 + asl * 16);
  const char* B0 = lds + (12288 + (wn * 144 + lrow) * 64 + asl * 16);

  f32x4 acc[3][9] = {};

  // ---- prologue: fill bufs 0,1; make buf0 visible to all waves ----
  STAGE2A_(0, 0); STAGE2B_(0, 0);
  STAGE2A_(1, 1); STAGE2B_(1, 1);
  asm volatile("s_waitcnt vmcnt(4)" ::: "memory");   // buf0 landed (all 4 per wave)
  __builtin_amdgcn_s_barrier();

#pragma unroll
  for (int kt = 0; kt < 16; ++kt) {
    const int bo = (kt & 3) * 32768;
    bf16x8 af[3], bfv[9];

    // ================= phase A =================
#pragma unroll
    for (int mt = 0; mt < 3; ++mt) af[mt] = *(const bf16x8*)(A0 + bo + mt * 1024);
#pragma unroll
    for (int nt = 0; nt < 4; ++nt) bfv[nt] = *(const bf16x8*)(B0 + bo + nt * 1024);
    if (kt < 14) STAGE2A_(kt + 2, (kt + 2) & 3);
    __builtin_amdgcn_s_barrier();
    asm volatile("s_waitcnt lgkmcnt(0)" ::: "memory");
    __builtin_amdgcn_sched_barrier(0);
    __builtin_amdgcn_s_setprio(1);
#pragma unroll
    for (int mt = 0; mt < 3; ++mt)
#pragma unroll
      for (int nt = 0; nt < 4; ++nt)
        // swapped operands: D row = l (quad*4+reg), D col = m (lane&15)
        acc[mt][nt] = __builtin_amdgcn_mfma_f32_16x16x32_bf16(bfv[nt], af[mt],
                                                              acc[mt][nt], 0, 0, 0);
    __builtin_amdgcn_s_setprio(0);

    // ================= phase B =================
#pragma unroll
    for (int nt = 4; nt < 9; ++nt) bfv[nt] = *(const bf16x8*)(B0 + bo + nt * 1024);
    if (kt < 14) STAGE2B_(kt + 2, (kt + 2) & 3);
    __builtin_amdgcn_s_barrier();
    asm volatile("s_waitcnt lgkmcnt(0)" ::: "memory");
    __builtin_amdgcn_sched_barrier(0);
    __builtin_amdgcn_s_setprio(1);
#pragma unroll
    for (int mt = 0; mt < 3; ++mt)
#pragma unroll
      for (int nt = 4; nt < 9; ++nt)
        acc[mt][nt] = __builtin_amdgcn_mfma_f32_16x16x32_bf16(bfv[nt], af[mt],
                                                              acc[mt][nt], 0, 0, 0);
    __builtin_amdgcn_s_setprio(0);

    // ========== end of body: retire buf[kt+1] for every wave ==========
    if (kt < 14) {
      asm volatile("s_waitcnt vmcnt(4)" ::: "memory");
    } else if (kt == 14) {
      asm volatile("s_waitcnt vmcnt(0)" ::: "memory");
    }
    __builtin_amdgcn_s_barrier();
  }
#undef STAGE2A_
#undef STAGE2B_

  // ---- epilogue A: acc -> LDS U-tile (bf16, stride 296; unions dead ring) ----
  // (final end-of-body barrier separates all waves' LDS reads from Ut writes)
  unsigned short* Ut = (unsigned short*)lds;
#pragma unroll
  for (int mt = 0; mt < 3; ++mt) {
    const int m = wm * 48 + mt * 16 + lrow;          // m = kk*64 + e_local
#pragma unroll
    for (int nt = 0; nt < 9; ++nt) {
      const int lcol = wn * 144 + nt * 16 + (lc << 2);
      uint2 pk;
      pk.x = (unsigned int)f2bf(acc[mt][nt][0]) | ((unsigned int)f2bf(acc[mt][nt][1]) << 16);
      pk.y = (unsigned int)f2bf(acc[mt][nt][2]) | ((unsigned int)f2bf(acc[mt][nt][3]) << 16);
      *(uint2*)&Ut[m * 296 + lcol] = pk;
    }
  }
  __syncthreads();

  // ---- epilogue B: AA combine + biases, store out ----
  // thread t: e_local = t>>3, l-chunk base = (t&7)*32 (thread owns a 256B strip)
  const int el  = tid >> 3;
  const int lt0 = (tid & 7) << 5;
  const int e   = e0 + el;
  const float pcb = Pcb[e];
  const float pb  = proj_b[e];
  float sa[17];
#pragma unroll
  for (int j = 0; j < 17; ++j) sa[j] = aa[j];
  const unsigned short* u0r = Ut + (size_t)el * 296;          // kk=0
  const unsigned short* u1r = Ut + (size_t)(64 + el) * 296;   // kk=1
  const unsigned short* u2r = Ut + (size_t)(128 + el) * 296;  // kk=2
  const bool edge = (L0 == 0) || (L0 == 3840);
  float* orow = out + (((size_t)(bb * 512 + e)) << 13) + 2 * (size_t)(L0 + lt0);

#pragma unroll
  for (int cc = 0; cc < 4; ++cc) {
    const int c0 = lt0 + 8 * cc + 12;   // Ut col of E[0]  (c = l - l0g = c0 + j)
    float E[17], O[16];
    if (!edge) {
      // interior: aligned 16B window [c0-4, c0+20) covers all needed cols
      const u16x8 e0v = *(const u16x8*)(u1r + c0 - 4);
      const u16x8 e1v = *(const u16x8*)(u1r + c0 + 4);
      const u16x8 e2v = *(const u16x8*)(u1r + c0 + 12);
      const u16x8 a0v = *(const u16x8*)(u0r + c0 - 4);
      const u16x8 a1v = *(const u16x8*)(u0r + c0 + 4);
      const u16x8 a2v = *(const u16x8*)(u0r + c0 + 12);
      const u16x8 b0v = *(const u16x8*)(u2r + c0 - 4);
      const u16x8 b1v = *(const u16x8*)(u2r + c0 + 4);
      const u16x8 b2v = *(const u16x8*)(u2r + c0 + 12);
      unsigned short ue[24], ua[24], ub[24];
#pragma unroll
      for (int j = 0; j < 8; ++j) {
        ue[j] = e0v[j]; ue[j + 8] = e1v[j]; ue[j + 16] = e2v[j];
        ua[j] = a0v[j]; ua[j + 8] = a1v[j]; ua[j + 16] = a2v[j];
        ub[j] = b0v[j]; ub[j + 8] = b1v[j]; ub[j + 16] = b2v[j];
      }
#pragma unroll
      for (int j = 0; j < 17; ++j) E[j] = bf2f(ue[4 + j]) + pcb;
#pragma unroll
      for (int j = 0; j < 16; ++j) O[j] = bf2f(ua[4 + j]) + pcb + bf2f(ub[5 + j]);
    } else {
      const int lt = L0 + lt0 + 8 * cc;
#pragma unroll
      for (int j = 0; j < 17; ++j) {
        const int l = lt - 4 + j;
        E[j] = (l >= 0 && l < 4096) ? (bf2f(u1r[c0 + j]) + pcb) : 0.f;
      }
#pragma unroll
      for (int j = 0; j < 16; ++j) {
        const int l = lt - 4 + j;
        float v = 0.f;
        if (l >= 0 && l < 4096) {
          v = bf2f(u0r[c0 + j]) + pcb;
          if (l + 1 < 4096) v += bf2f(u2r[c0 + j + 1]);
        }
        O[j] = v;
      }
    }
    float res[16];
#pragma unroll
    for (int t = 0; t < 8; ++t) {
      float se = 0.f, so = 0.f;
#pragma unroll
      for (int q = 0; q <= 8; ++q) {   // even taps
        se += sa[2 * q] * E[t + q];
        so += sa[2 * q] * O[t + q];
      }
#pragma unroll
      for (int q = 0; q < 8; ++q) {    // odd taps
        se += sa[2 * q + 1] * O[t + q];
        so += sa[2 * q + 1] * E[t + q + 1];
      }
      res[2 * t]     = se + pb;
      res[2 * t + 1] = so + pb;
    }
#pragma unroll
    for (int c2 = 0; c2 < 4; ++c2)
      *(float4*)(orow + 16 * cc + 4 * c2) = *(const float4*)&res[4 * c2];
  }
}

// ---------------------------------------------------------------------------
extern "C" void kernel_launch(void* const* d_in, const int* in_sizes, int n_in,
                              void* d_out, int out_size, void* d_ws, size_t ws_size,
                              hipStream_t stream) {
  const float* x      = (const float*)d_in[0];
  const float* conv_w = (const float*)d_in[1];
  const float* conv_b = (const float*)d_in[2];
  const float* aa     = (const float*)d_in[3];
  const float* proj_w = (const float*)d_in[4];
  const float* proj_b = (const float*)d_in[5];
  float* out = (float*)d_out;

  char* ws = (char*)d_ws;
  unsigned short* Mst = (unsigned short*)ws;              //  1,572,864 B
  float*          Pcb = (float*)(ws + 1572864);           //      2,048 B
  unsigned short* Xbt = (unsigned short*)(ws + 1574912);  // 33,554,432 B (tot 35.1MB)

  k_prep<<<dim3(4416, 1, 1), 256, 0, stream>>>(proj_w, conv_w, conv_b, x, Mst, Pcb, Xbt);
  k_fused<<<dim3(1024, 1, 1), 512, 0, stream>>>(Xbt, Mst, Pcb, aa, proj_b, out);
}